// Round 5
// baseline (129.354 us; speedup 1.0000x reference)
//
#include <hip/hip_runtime.h>

// RNN: h_t = tanh(x_t*w_ih + b_ih + b_hh + W_hh h_{t-1});  out = h_T . w_fc + b_fc
// B=4096, T=512, I=1, H=16, O=1.
//
// Layout: 32 lanes per batch element -> 131072 threads -> 2 waves/SIMD.
//   Wave rows (16 lanes each): rows {0,1} = batch A, rows {2,3} = batch B.
//   Every lane holds a plain copy of h[lane&15].
//   Row-even lane l accumulates output o=l over rotation offsets r=0..7 AND
//   owns the x/bias term. Row-odd lane l accumulates output o=(l+8)&15 over
//   the SAME rotations (covering offsets 8..15 of o) with NO x/bias term
//   (round-1 bug: both rows added it -> doubled input). A row-masked ror8 DPP
//   on the partial re-aligns row-odd partials to output index (lane&15), then
//   permlane16 swap+add completes the 16-term dot in every lane. All lanes
//   compute tanh, restoring the plain-h invariant for free.
// tanh prescale 2*log2(e) folded into all weights/biases:
//   tanh(s) = 1 - 2/(exp2(s')+1), s' = 2*log2(e)*s.

constexpr int T_STEPS = 512;
constexpr float C2LE = 2.8853900817779268f; // 2*log2(e)

#define DPP_ROR(r, src) __builtin_amdgcn_update_dpp(0, (src), 0x120 + (r), 0xF, 0xF, false)
// ror8 applied to rows 1,3 only (row_mask 0xA); masked-off rows keep `old_`.
#define DPP_ROR8_ODDROWS(old_, src_) __builtin_amdgcn_update_dpp((old_), (src_), 0x128, 0xA, 0xF, false)

__device__ __forceinline__ float xor16_sum(float p) {
#if __has_builtin(__builtin_amdgcn_permlane16_swap)
    // (a,b) = permlane16_swap(p,p): a+b == p[lane] + p[lane^16] in every lane
    // (VALU pipe, no DS traffic in the serial chain).
    auto pr = __builtin_amdgcn_permlane16_swap((unsigned)__float_as_int(p),
                                               (unsigned)__float_as_int(p),
                                               false, false);
    return __int_as_float((int)pr[0]) + __int_as_float((int)pr[1]);
#else
    // Fallback: ds_swizzle xor-16 (BitMode: (16<<10)|0x1F).
    int o_ = __builtin_amdgcn_ds_swizzle(__float_as_int(p), 0x401F);
    return p + __int_as_float(o_);
#endif
}

__global__ __launch_bounds__(256) void rnn_fused(
    const float* __restrict__ x,
    const float* __restrict__ w_ih,
    const float* __restrict__ w_hh,
    const float* __restrict__ b_ih,
    const float* __restrict__ b_hh,
    const float* __restrict__ w_fc,
    const float* __restrict__ b_fc,
    float* __restrict__ out)
{
    const int tid     = blockIdx.x * blockDim.x + threadIdx.x;
    const int b       = tid >> 5;                 // batch element (32 lanes each)
    const int lane    = threadIdx.x & 63;         // wave lane
    const int l       = lane & 15;                // position within 16-lane row
    const int row_odd = (lane >> 4) & 1;          // odd row of the batch's pair
    const int o       = (l + (row_odd << 3)) & 15;// output unit this lane accumulates

    // x/bias term is owned by the even row ONLY (odd row's 8 W_hh terms are
    // its entire contribution) — gating at setup costs nothing per step.
    const float wihc  = row_odd ? 0.0f : w_ih[o] * C2LE;
    const float biasc = row_odd ? 0.0f : (b_ih[o] + b_hh[o]) * C2LE;

    // Direction-proof weight gather: push the held h-index (l) through the same
    // DPP rotations used on h, so wr[r] matches whatever lane DPP sources.
    float wr[8];
    {
        const int base = o << 4;                  // w_hh row o (H x H row-major)
        wr[0] = w_hh[base + l] * C2LE;            // r=0: own value h[l]
        #define WSETUP(r) { int s_ = DPP_ROR(r, l); wr[r] = w_hh[base + s_] * C2LE; }
        WSETUP(1) WSETUP(2) WSETUP(3) WSETUP(4) WSETUP(5) WSETUP(6) WSETUP(7)
        #undef WSETUP
    }

    const float* xb = x + ((size_t)b << 9);       // x[b,:,0], 512 floats, 16B aligned
    float h = 0.0f;

    #define STEP(xval) {                                                   \
        const int hb = __float_as_int(h);                                  \
        const int d1 = DPP_ROR(1, hb), d2 = DPP_ROR(2, hb);                \
        const int d3 = DPP_ROR(3, hb), d4 = DPP_ROR(4, hb);                \
        const int d5 = DPP_ROR(5, hb), d6 = DPP_ROR(6, hb);                \
        const int d7 = DPP_ROR(7, hb);                                     \
        float p0 = fmaf((xval), wihc, biasc);                              \
        p0 = fmaf(h, wr[0], p0);                                           \
        float p1 = __int_as_float(d1) * wr[1];                             \
        p0 = fmaf(__int_as_float(d2), wr[2], p0);                          \
        p1 = fmaf(__int_as_float(d3), wr[3], p1);                          \
        p0 = fmaf(__int_as_float(d4), wr[4], p0);                          \
        p1 = fmaf(__int_as_float(d5), wr[5], p1);                          \
        p0 = fmaf(__int_as_float(d6), wr[6], p0);                          \
        p1 = fmaf(__int_as_float(d7), wr[7], p1);                          \
        float P = p0 + p1;                                                 \
        P = __int_as_float(DPP_ROR8_ODDROWS(__float_as_int(P),             \
                                            __float_as_int(P)));           \
        const float s_ = xor16_sum(P);   /* full scaled dot, every lane */ \
        const float e_ = __builtin_amdgcn_exp2f(s_);                       \
        const float rc = __builtin_amdgcn_rcpf(e_ + 1.0f);                 \
        h = fmaf(-2.0f, rc, 1.0f);       /* every lane: h[lane&15] */      \
    }

    // 8 steps/iter; next x block prefetched as 2x float4 (L1-resident).
    float4 cur0 = *reinterpret_cast<const float4*>(xb);
    float4 cur1 = *reinterpret_cast<const float4*>(xb + 4);
    #pragma unroll 1
    for (int tb = 0; tb < T_STEPS; tb += 8) {
        const int nxt = (tb + 8 < T_STEPS) ? (tb + 8) : 0;  // last iter: dummy
        const float4 n0 = *reinterpret_cast<const float4*>(xb + nxt);
        const float4 n1 = *reinterpret_cast<const float4*>(xb + nxt + 4);
        STEP(cur0.x) STEP(cur0.y) STEP(cur0.z) STEP(cur0.w)
        STEP(cur1.x) STEP(cur1.y) STEP(cur1.z) STEP(cur1.w)
        cur0 = n0; cur1 = n1;
    }
    #undef STEP

    // out[b] = dot(h, w_fc) + b_fc. Every lane holds h[l]; butterfly within
    // the 16-lane row (xor 8/4/2/1 never cross rows). Lane 0 of each 32-lane
    // group writes.
    float v = h * w_fc[l];
    v += __shfl_xor(v, 8);
    v += __shfl_xor(v, 4);
    v += __shfl_xor(v, 2);
    v += __shfl_xor(v, 1);
    if ((lane & 31) == 0) out[b] = v + b_fc[0];
}

extern "C" void kernel_launch(void* const* d_in, const int* in_sizes, int n_in,
                              void* d_out, int out_size, void* d_ws, size_t ws_size,
                              hipStream_t stream) {
    const float* x    = (const float*)d_in[0];
    const float* w_ih = (const float*)d_in[1];
    const float* w_hh = (const float*)d_in[2];
    const float* b_ih = (const float*)d_in[3];
    const float* b_hh = (const float*)d_in[4];
    const float* w_fc = (const float*)d_in[5];
    const float* b_fc = (const float*)d_in[6];
    float* out = (float*)d_out;

    const int B = out_size;                       // 4096
    const int threads = 256;
    const int blocks  = (B * 32) / threads;       // 512 blocks -> 2 waves/SIMD
    rnn_fused<<<blocks, threads, 0, stream>>>(x, w_ih, w_hh, b_ih, b_hh, w_fc, b_fc, out);
}

// Round 7
// 100.318 us; speedup vs baseline: 1.2894x; 1.2894x over previous
//
#include <hip/hip_runtime.h>

// RNN: h_t = tanh(x_t*w_ih + b_ih + b_hh + W_hh h_{t-1});  out = h_T . w_fc + b_fc
// B=4096, T=512, I=1, H=16, O=1.
//
// Round 3: back to the minimal-work 16-lane-per-batch layout (round 0), with
// the 15 standalone DPP movs fused into the FMAs via inline-asm
// v_mul_f32_dpp / v_fmac_f32_dpp (single 2-cycle issue each). Round-0's
// builtin-update_dpp version paid mov-zero + mov_dpp per rotation (~53
// effective insts/step); this is ~24.
//
// Direction-proofing: wr[r] is gathered at setup by pushing the lane index
// through __builtin_amdgcn_update_dpp with ctrl 0x120+r — the EXACT ctrl the
// asm's row_ror:r encodes — so whichever direction the HW rotates, weight and
// h-value stay paired (this is what made rounds 0/2 numerically correct).
//
// tanh prescale 2*log2(e) folded into all weights/biases:
//   tanh(s) = 1 - 2/(exp2(s')+1), s' = 2*log2(e)*s.

constexpr int T_STEPS = 512;
constexpr float C2LE = 2.8853900817779268f; // 2*log2(e)

#define DPP_CTRL_ROR(r) (0x120 + (r))
#define DPP_ROR_IDX(r, src) __builtin_amdgcn_update_dpp(0, (src), DPP_CTRL_ROR(r), 0xF, 0xF, false)

__global__ __launch_bounds__(256) void rnn_fused(
    const float* __restrict__ x,
    const float* __restrict__ w_ih,
    const float* __restrict__ w_hh,
    const float* __restrict__ b_ih,
    const float* __restrict__ b_hh,
    const float* __restrict__ w_fc,
    const float* __restrict__ b_fc,
    float* __restrict__ out)
{
    const int tid = blockIdx.x * blockDim.x + threadIdx.x;
    const int b   = tid >> 4;   // batch element (16 lanes each)
    const int me  = tid & 15;   // hidden unit owned by this lane

    const float wihc  = w_ih[me] * C2LE;
    const float biasc = (b_ih[me] + b_hh[me]) * C2LE;
    const float wfc   = w_fc[me];

    // Weight gather through the same DPP network the step asm uses.
    float wr[16];
    {
        const int base = me << 4;            // w_hh row 'me' (H x H row-major)
        wr[0] = w_hh[base + me] * C2LE;
        #define WSETUP(r) { int s_ = DPP_ROR_IDX(r, me); wr[r] = w_hh[base + s_] * C2LE; }
        WSETUP(1)  WSETUP(2)  WSETUP(3)  WSETUP(4)  WSETUP(5)
        WSETUP(6)  WSETUP(7)  WSETUP(8)  WSETUP(9)  WSETUP(10)
        WSETUP(11) WSETUP(12) WSETUP(13) WSETUP(14) WSETUP(15)
        #undef WSETUP
    }
    const float w1 = wr[1],  w2 = wr[2],  w3 = wr[3],  w4 = wr[4],  w5 = wr[5];
    const float w6 = wr[6],  w7 = wr[7],  w8 = wr[8],  w9 = wr[9],  w10 = wr[10];
    const float w11 = wr[11], w12 = wr[12], w13 = wr[13], w14 = wr[14], w15 = wr[15];
    const float w0 = wr[0];

    const float* xb = x + ((size_t)b << 9);  // x[b,:,0], 512 floats, 16B aligned
    float h = 0.0f;

    // One timestep. a0..a3: 4 round-robin accumulator chains (same-acc ops 4
    // slots apart -> HW interlocks suffice). s_nop 1 covers the mandatory
    // 2-wait-state VALU-write(h) -> DPP-read hazard (opaque to the compiler).
    #define STEP(xval) {                                                      \
        float a0 = fmaf((xval), wihc, biasc);                                 \
        a0 = fmaf(h, w0, a0);                                                 \
        float a1, a2, a3;                                                     \
        asm volatile(                                                         \
          "s_nop 1\n\t"                                                       \
          "v_mul_f32_dpp %0, %4, %5 row_ror:1 row_mask:0xf bank_mask:0xf\n\t" \
          "v_mul_f32_dpp %1, %4, %6 row_ror:2 row_mask:0xf bank_mask:0xf\n\t" \
          "v_mul_f32_dpp %2, %4, %7 row_ror:3 row_mask:0xf bank_mask:0xf\n\t" \
          "v_fmac_f32_dpp %3, %4, %8 row_ror:4 row_mask:0xf bank_mask:0xf\n\t"\
          "v_fmac_f32_dpp %0, %4, %9 row_ror:5 row_mask:0xf bank_mask:0xf\n\t"\
          "v_fmac_f32_dpp %1, %4, %10 row_ror:6 row_mask:0xf bank_mask:0xf\n\t"\
          "v_fmac_f32_dpp %2, %4, %11 row_ror:7 row_mask:0xf bank_mask:0xf\n\t"\
          "v_fmac_f32_dpp %3, %4, %12 row_ror:8 row_mask:0xf bank_mask:0xf\n\t"\
          "v_fmac_f32_dpp %0, %4, %13 row_ror:9 row_mask:0xf bank_mask:0xf\n\t"\
          "v_fmac_f32_dpp %1, %4, %14 row_ror:10 row_mask:0xf bank_mask:0xf\n\t"\
          "v_fmac_f32_dpp %2, %4, %15 row_ror:11 row_mask:0xf bank_mask:0xf\n\t"\
          "v_fmac_f32_dpp %3, %4, %16 row_ror:12 row_mask:0xf bank_mask:0xf\n\t"\
          "v_fmac_f32_dpp %0, %4, %17 row_ror:13 row_mask:0xf bank_mask:0xf\n\t"\
          "v_fmac_f32_dpp %1, %4, %18 row_ror:14 row_mask:0xf bank_mask:0xf\n\t"\
          "v_fmac_f32_dpp %2, %4, %19 row_ror:15 row_mask:0xf bank_mask:0xf"  \
          : "=&v"(a1), "=&v"(a2), "=&v"(a3), "+v"(a0)                         \
          : "v"(h), "v"(w1), "v"(w2), "v"(w3), "v"(w4), "v"(w5), "v"(w6),     \
            "v"(w7), "v"(w8), "v"(w9), "v"(w10), "v"(w11), "v"(w12),          \
            "v"(w13), "v"(w14), "v"(w15));                                    \
        const float s_ = (a0 + a1) + (a2 + a3);   /* pre-scaled by 2*log2e */ \
        const float e_ = __builtin_amdgcn_exp2f(s_);                          \
        const float rc = __builtin_amdgcn_rcpf(e_ + 1.0f);                    \
        h = fmaf(-2.0f, rc, 1.0f);                                            \
    }

    // 8 steps/iter; next x block prefetched as 2x float4 (L1-resident,
    // 16 lanes same address -> broadcast).
    float4 cur0 = *reinterpret_cast<const float4*>(xb);
    float4 cur1 = *reinterpret_cast<const float4*>(xb + 4);
    #pragma unroll 1
    for (int tb = 0; tb < T_STEPS; tb += 8) {
        const int nxt = (tb + 8 < T_STEPS) ? (tb + 8) : 0;  // last iter: dummy
        const float4 n0 = *reinterpret_cast<const float4*>(xb + nxt);
        const float4 n1 = *reinterpret_cast<const float4*>(xb + nxt + 4);
        STEP(cur0.x) STEP(cur0.y) STEP(cur0.z) STEP(cur0.w)
        STEP(cur1.x) STEP(cur1.y) STEP(cur1.z) STEP(cur1.w)
        cur0 = n0; cur1 = n1;
    }
    #undef STEP

    // out[b] = dot(h, w_fc) + b_fc — butterfly within the 16-lane group.
    float v = h * wfc;
    v += __shfl_xor(v, 8);
    v += __shfl_xor(v, 4);
    v += __shfl_xor(v, 2);
    v += __shfl_xor(v, 1);
    if (me == 0) out[b] = v + b_fc[0];
}

extern "C" void kernel_launch(void* const* d_in, const int* in_sizes, int n_in,
                              void* d_out, int out_size, void* d_ws, size_t ws_size,
                              hipStream_t stream) {
    const float* x    = (const float*)d_in[0];
    const float* w_ih = (const float*)d_in[1];
    const float* w_hh = (const float*)d_in[2];
    const float* b_ih = (const float*)d_in[3];
    const float* b_hh = (const float*)d_in[4];
    const float* w_fc = (const float*)d_in[5];
    const float* b_fc = (const float*)d_in[6];
    float* out = (float*)d_out;

    const int B = out_size;                  // 4096
    const int threads = 256;
    const int blocks  = (B * 16) / threads;  // 256 blocks -> 1/CU, 1 wave/SIMD
    rnn_fused<<<blocks, threads, 0, stream>>>(x, w_ih, w_hh, b_ih, b_hh, w_fc, b_fc, out);
}